// Round 6
// baseline (426.740 us; speedup 1.0000x reference)
//
#include <hip/hip_runtime.h>
#include <hip/hip_bf16.h>
#include <math.h>

// Problem constants (setup_inputs)
#define BQ   2
#define LQ   4096
#define CQ   1024
#define NHQ  16
#define DHQ  64
#define KSEL 1638
#define KPAD 1664
#define MTOT (BQ*KSEL)   // 3276
#define MPAD 3328        // 26*128

typedef short s16x8 __attribute__((ext_vector_type(8)));
typedef float fx4   __attribute__((ext_vector_type(4)));

#define MFMA16(a,b,c) __builtin_amdgcn_mfma_f32_16x16x32_bf16(a,b,c,0,0,0)

__device__ __forceinline__ float b2f(unsigned short u) {
  union { float f; unsigned int i; } cv; cv.i = ((unsigned int)u) << 16; return cv.f;
}
__device__ __forceinline__ unsigned short f2b(float f) {
  union { float f; unsigned int i; } cv; cv.f = f;
  unsigned int x = cv.i;
  return (unsigned short)((x + 0x7fffu + ((x >> 16) & 1u)) >> 16);
}
__device__ __forceinline__ unsigned int fbits(float f) {
  union { float f; unsigned int i; } cv; cv.f = f; return cv.i;
}
__device__ __forceinline__ void async16(const void* g, void* l) {
  __builtin_amdgcn_global_load_lds((const __attribute__((address_space(1))) void*)g,
                                   (__attribute__((address_space(3))) void*)l, 16, 0, 0);
}

// ---------------- fp32 -> bf16 conversion, fused over x / W_qkv / W_proj ----------------
__global__ __launch_bounds__(256) void k_cvt3(const float* __restrict__ x,
                                              const float* __restrict__ wqkv,
                                              const float* __restrict__ wproj,
                                              unsigned short* __restrict__ xb,
                                              unsigned short* __restrict__ wqb,
                                              unsigned short* __restrict__ wpb) {
  int i = blockIdx.x * 256 + threadIdx.x;   // float4 index, total 3145728
  const float* s; unsigned short* d; int off;
  if (i < 2097152)      { s = x;     d = xb;  off = i; }
  else if (i < 2883584) { s = wqkv;  d = wqb; off = i - 2097152; }
  else                  { s = wproj; d = wpb; off = i - 2883584; }
  float4 v = ((const float4*)s)[off];
  ushort4 o;
  o.x = f2b(v.x); o.y = f2b(v.y); o.z = f2b(v.z); o.w = f2b(v.w);
  ((ushort4*)d)[off] = o;
}

// ---------------- mean (fp64, 2-stage) ----------------
__global__ __launch_bounds__(256) void k_mean_part(const float* __restrict__ x,
                                                   double* __restrict__ part) {
  int bid = blockIdx.x;                    // 256 blocks: [b(2)][ch(32)][cb(4)]
  int cb = bid & 3, ch = (bid >> 2) & 31, b = bid >> 7;
  int c = cb * 256 + threadIdx.x;
  const float* p = x + ((size_t)b * LQ + (size_t)ch * 128) * CQ + c;
  double s = 0.0;
  for (int r = 0; r < 128; ++r) s += (double)p[(size_t)r * CQ];
  part[((size_t)b * 32 + ch) * CQ + c] = s;
}

__global__ __launch_bounds__(256) void k_mean_reduce(const double* __restrict__ part,
                                                     double* __restrict__ mean) {
  int g = blockIdx.x * 256 + threadIdx.x;  // 2048 = B*C
  int b = g >> 10, c = g & 1023;
  double s = 0.0;
  for (int ch = 0; ch < 32; ++ch) s += part[((size_t)b * 32 + ch) * CQ + c];
  mean[g] = s * (1.0 / 4096.0);
}

// ---------------- mse (fp64) + base output (x + upsample(cached)) ----------------
__global__ __launch_bounds__(256) void k_mse_base(const float* __restrict__ x,
                                                  const float* __restrict__ cached,
                                                  const double* __restrict__ mean,
                                                  double* __restrict__ mse,
                                                  float* __restrict__ out) {
  int bl = blockIdx.x; int b = bl >> 12, l = bl & 4095;
  int hh = l >> 6, ww = l & 63;
  size_t xoff = ((size_t)b * LQ + l) * CQ;
  size_t uoff = (((size_t)b * 32 + (hh >> 1)) * 32 + (ww >> 1)) * CQ;
  const double* mrow = mean + (size_t)b * CQ;
  int c0 = threadIdx.x * 4;
  float4 xv = *(const float4*)(x + xoff + c0);
  float4 uv = *(const float4*)(cached + uoff + c0);
  float4 ov;
  ov.x = xv.x + uv.x; ov.y = xv.y + uv.y; ov.z = xv.z + uv.z; ov.w = xv.w + uv.w;
  *(float4*)(out + xoff + c0) = ov;
  double d0 = (double)xv.x - mrow[c0];
  double d1 = (double)xv.y - mrow[c0 + 1];
  double d2 = (double)xv.z - mrow[c0 + 2];
  double d3 = (double)xv.w - mrow[c0 + 3];
  double ss = d0 * d0 + d1 * d1 + d2 * d2 + d3 * d3;
  for (int o = 1; o < 64; o <<= 1) ss += __shfl_xor(ss, o);
  __shared__ double ws4[4];
  if ((threadIdx.x & 63) == 0) ws4[threadIdx.x >> 6] = ss;
  __syncthreads();
  if (threadIdx.x == 0) mse[(size_t)b * LQ + l] = ws4[0] + ws4[1] + ws4[2] + ws4[3];
}

// ---------------- top-k: MSD radix select, per-wave privatized histograms ----------------
// Keys are low-entropy (all mse ~1024 +/- 45): a single shared histogram serializes on
// same-address LDS atomics (measured 106us). Per-wave hists with stride 257 (bank-skew)
// + ballot-aggregated extraction bring contention down to ~256 serial ops/wave worst case.
__global__ __launch_bounds__(1024) void k_topk(const double* __restrict__ mse,
                                               int* __restrict__ idx_sel) {
  __shared__ unsigned long long u[4096];       // 32 KB
  __shared__ unsigned int whist[16 * 257];     // 16.4 KB, stride 257 => cross-wave bank skew
  __shared__ unsigned long long sh_prefix;
  __shared__ int sh_rem, sh_cnt, sh_eqcnt;
  __shared__ int eqbuf[256];
  int b = blockIdx.x, t = threadIdx.x;
  int wv = t >> 6, laneid = t & 63;
  for (int p = 0; p < 4; ++p) {
    int i = p * 1024 + t;
    u[i] = (unsigned long long)__double_as_longlong(mse[(size_t)b * LQ + i]);
  }
  if (t == 0) { sh_prefix = 0ULL; sh_rem = KSEL; sh_cnt = 0; sh_eqcnt = 0; }
  __syncthreads();
  for (int shift = 56; shift >= 0; shift -= 8) {
    for (int z = t; z < 16 * 257; z += 1024) whist[z] = 0u;
    __syncthreads();
    unsigned long long pref = sh_prefix;
#pragma unroll
    for (int p = 0; p < 4; ++p) {
      int i = p * 1024 + t;
      unsigned long long v = u[i];
      bool cand = (shift == 56) || ((v >> ((shift + 8) & 63)) == pref);
      if (cand) atomicAdd(&whist[wv * 257 + ((unsigned int)(v >> shift) & 255u)], 1u);
    }
    __syncthreads();
    if (t < 256) {            // reduce wave hists; whist[t] (wave0 bin t) read+written by thread t only
      unsigned int s = 0;
#pragma unroll
      for (int wvi = 0; wvi < 16; ++wvi) s += whist[wvi * 257 + t];
      whist[t] = s;
    }
    __syncthreads();
    if (t == 0) {
      int rem = sh_rem;
      int acc = 0, bsel = 0;
      for (int bin = 255; bin >= 0; --bin) {
        int c = (int)whist[bin];
        if (acc + c >= rem) { bsel = bin; sh_rem = rem - acc; break; }
        acc += c;
      }
      sh_prefix = (sh_prefix << 8) | (unsigned long long)bsel;
    }
    __syncthreads();
  }
  unsigned long long T = sh_prefix;
  int rem_eq = sh_rem;
#pragma unroll
  for (int p = 0; p < 4; ++p) {
    int i = p * 1024 + t;
    unsigned long long v = u[i];
    bool win = (v > T);
    unsigned long long mask = __ballot(win);
    int total = __popcll(mask);
    int base = 0;
    if (laneid == 0 && total > 0) base = atomicAdd(&sh_cnt, total);
    base = __shfl(base, 0);
    if (win) {
      int lpos = __popcll(mask & ((1ULL << laneid) - 1ULL));
      idx_sel[b * KPAD + base + lpos] = i;
    }
    if (v == T) {
      int e = atomicAdd(&sh_eqcnt, 1);
      if (e < 256) eqbuf[e] = i;
    }
  }
  __syncthreads();
  if (t == 0) {
    int n = sh_eqcnt; if (n > 256) n = 256;
    for (int a = 1; a < n; ++a) {           // ascending index sort (ties: smallest index wins)
      int key = eqbuf[a]; int c = a - 1;
      while (c >= 0 && eqbuf[c] > key) { eqbuf[c + 1] = eqbuf[c]; --c; }
      eqbuf[c + 1] = key;
    }
    int base = sh_cnt;
    for (int a = 0; a < rem_eq && a < n; ++a) idx_sel[b * KPAD + base + a] = eqbuf[a];
    for (int a = KSEL; a < KPAD; ++a) idx_sel[b * KPAD + a] = 0;
  }
}

// ---------------- GEMM (m97-style 128x128, BK=32, global_load_lds w16) ----------------
template<int MODE>
__global__ __launch_bounds__(256) void k_gemm(const unsigned short* __restrict__ Asrc,
                                              const unsigned short* __restrict__ Bmat,
                                              const int* __restrict__ idx_sel,
                                              unsigned short* __restrict__ Cbf,
                                              float* __restrict__ Cf,
                                              const float* __restrict__ xin,
                                              const float* __restrict__ bproj) {
  int bm = blockIdx.x % 26, bn = blockIdx.x / 26;
  int tid = threadIdx.x;
  int w = tid >> 6, lane = tid & 63, quad = lane >> 4, l15 = lane & 15;
  int wm = w & 1, wn = w >> 1;
  __shared__ __align__(16) unsigned char sm[16384];   // A [128][32]bf16, B [128][32]bf16

  const unsigned short* gA[2];
  const unsigned short* gB[2];
#pragma unroll
  for (int p = 0; p < 2; ++p) {
    int e = p * 256 + tid; int row = e >> 2, kc = e & 3;
    int m = bm * 128 + row; if (m >= MTOT) m = MTOT - 1;
    int bb = m / KSEL; int ii = m - bb * KSEL;
    const unsigned short* rp;
    if (MODE == 0) {
      int lsel = idx_sel[bb * KPAD + ii];
      rp = Asrc + ((size_t)bb * LQ + lsel) * CQ;
    } else {
      rp = Asrc + ((size_t)bb * KPAD + ii) * CQ;
    }
    gA[p] = rp + kc * 8;
    gB[p] = Bmat + (size_t)(bn * 128 + row) * CQ + kc * 8;
  }

  fx4 acc[4][4];
#pragma unroll
  for (int a = 0; a < 4; ++a)
#pragma unroll
    for (int c = 0; c < 4; ++c) acc[a][c] = (fx4){0.f, 0.f, 0.f, 0.f};

  for (int it = 0; it < 32; ++it) {
    int ke = it * 32;
    __syncthreads();
#pragma unroll
    for (int p = 0; p < 2; ++p) {
      async16(gA[p] + ke, sm + p * 4096 + w * 1024);
      async16(gB[p] + ke, sm + 8192 + p * 4096 + w * 1024);
    }
    __syncthreads();
    s16x8 af[4], bf[4];
#pragma unroll
    for (int mt = 0; mt < 4; ++mt)
      af[mt] = *(const s16x8*)(sm + ((wm * 64 + mt * 16 + l15) * 64 + quad * 16));
#pragma unroll
    for (int nt = 0; nt < 4; ++nt)
      bf[nt] = *(const s16x8*)(sm + 8192 + ((wn * 64 + nt * 16 + l15) * 64 + quad * 16));
#pragma unroll
    for (int mt = 0; mt < 4; ++mt)
#pragma unroll
      for (int nt = 0; nt < 4; ++nt)
        acc[mt][nt] = MFMA16(af[mt], bf[nt], acc[mt][nt]);
  }

#pragma unroll
  for (int mt = 0; mt < 4; ++mt)
#pragma unroll
    for (int nt = 0; nt < 4; ++nt) {
      int n = bn * 128 + wn * 64 + nt * 16 + l15;
      int mbase = bm * 128 + wm * 64 + mt * 16 + quad * 4;
      fx4 vv = acc[mt][nt];
      if (MODE == 0) {
#pragma unroll
        for (int r = 0; r < 4; ++r) {
          int m = mbase + r;
          if (m < MTOT) Cbf[(size_t)m * 3072 + n] = f2b(vv[r]);
        }
      } else {
        float bp = bproj[n];
#pragma unroll
        for (int r = 0; r < 4; ++r) {
          int m = mbase + r;
          if (m < MTOT) {
            int bb = m / KSEL; int ii = m - bb * KSEL;
            int lsel = idx_sel[bb * KPAD + ii];
            size_t off = ((size_t)bb * LQ + lsel) * CQ + n;
            Cf[off] = xin[off] + vv[r] + bp;
          }
        }
      }
    }
}

// ---------------- l2norm + scale + rope -> q,k ; v -> Vt (transposed) ----------------
__global__ __launch_bounds__(256) void k_normrope(const unsigned short* __restrict__ qkv,
                                                  const int* __restrict__ idx_sel,
                                                  const float* __restrict__ qbias,
                                                  const float* __restrict__ vbias,
                                                  const float* __restrict__ sml,
                                                  const float* __restrict__ rope,
                                                  unsigned short* __restrict__ qo,
                                                  unsigned short* __restrict__ ko,
                                                  unsigned short* __restrict__ vt) {
  int bid = blockIdx.x;                       // 26*16*2
  int tile = bid % 26; int h = (bid / 26) & 15; int b = bid / (26 * 16);
  int tid = threadIdx.x; int w = tid >> 6; int d = tid & 63;
  __shared__ unsigned short vtile[64 * 68];
  float scale = expf(fminf(sml[h], 4.6051702f));
  float qb = qbias[h * 64 + d];
  float vb = vbias[h * 64 + d];
  for (int pass = 0; pass < 16; ++pass) {
    int il = pass * 4 + w;
    int i = tile * 64 + il;
    float vraw = 0.f;
    if (i < KSEL) {
      int lsel = idx_sel[b * KPAD + i];
      size_t base = ((size_t)(b * KSEL + i)) * 3072 + h * 64 + d;
      int tt = d >> 1;
      float r0 = rope[(size_t)lsel * 32 + tt];
      float r1 = rope[(size_t)LQ * 32 + (size_t)lsel * 32 + tt];
      // q
      float qv = b2f(qkv[base]) + qb;
      float ss = qv * qv;
      for (int o = 1; o < 64; o <<= 1) ss += __shfl_xor(ss, o);
      float qn = qv / fmaxf(sqrtf(ss), 1e-12f) * scale;
      float qp = __shfl_xor(qn, 1);
      float qr = (d & 1) ? (r1 * qp + r0 * qn) : (r0 * qn - r1 * qp);
      qo[((size_t)(b * NHQ + h) * KPAD + i) * 64 + d] = f2b(qr);
      // k
      float kv = b2f(qkv[base + 1024]);
      float ks = kv * kv;
      for (int o = 1; o < 64; o <<= 1) ks += __shfl_xor(ks, o);
      float kn = kv / fmaxf(sqrtf(ks), 1e-12f);
      float kp = __shfl_xor(kn, 1);
      float kr = (d & 1) ? (r1 * kp + r0 * kn) : (r0 * kn - r1 * kp);
      ko[((size_t)(b * NHQ + h) * KPAD + i) * 64 + d] = f2b(kr);
      vraw = b2f(qkv[base + 2048]) + vb;
    }
    vtile[d * 68 + il] = f2b(vraw);
  }
  __syncthreads();
  int row = tid >> 2, c0 = (tid & 3) * 16;
  s16x8 o0, o1;
#pragma unroll
  for (int jj = 0; jj < 8; ++jj) {
    o0[jj] = (short)vtile[row * 68 + c0 + jj];
    o1[jj] = (short)vtile[row * 68 + c0 + 8 + jj];
  }
  size_t doff = ((size_t)((b * NHQ + h) * 64 + row)) * KPAD + (size_t)tile * 64 + c0;
  *(s16x8*)(vt + doff) = o0;
  *(s16x8*)(vt + doff + 8) = o1;
}

// ---------------- flash attention: S^T trick + LDS staging + coalesced epilogue ----------------
__global__ __launch_bounds__(256, 4) void k_attn(const unsigned short* __restrict__ qb,
                                                 const unsigned short* __restrict__ kb,
                                                 const unsigned short* __restrict__ vtb,
                                                 const float* __restrict__ sml,
                                                 unsigned short* __restrict__ pO,
                                                 float* __restrict__ pl) {
  int qt = blockIdx.x; int bh = blockIdx.y; int part = blockIdx.z;
  int b = bh >> 4, h = bh & 15;
  int t0 = part ? 7 : 0, t1 = part ? 13 : 7;
  int q0 = qt * 128;
  int tid = threadIdx.x, w = tid >> 6, lane = tid & 63, quad = lane >> 4, l15 = lane & 15;
  float M = __expf(fminf(sml[h], 4.6051702f));   // |S| <= scale, fixed softmax shift
  __shared__ __align__(16) unsigned short Kt[128 * 72];    // 18432 B
  __shared__ __align__(16) unsigned short Vt[64 * 136];    // 17408 B
  __shared__ __align__(16) unsigned short Pq[4][32 * 72];  // 18432 B  (total 54272 -> 3 blk/CU)
  unsigned short* Pw = Pq[w];
  const unsigned short* qbase = qb + (size_t)(b * NHQ + h) * KPAD * 64;
  const unsigned short* kbase = kb + (size_t)(b * NHQ + h) * KPAD * 64;
  const unsigned short* vbase = vtb + (size_t)(b * NHQ + h) * 64 * KPAD;

  // Q as B-operand: n=l15 -> q row; k = kb2*32 + quad*8
  s16x8 qf[2][2];
#pragma unroll
  for (int qtile = 0; qtile < 2; ++qtile)
#pragma unroll
    for (int kb2 = 0; kb2 < 2; ++kb2) {
      int row = q0 + w * 32 + qtile * 16 + l15;
      qf[qtile][kb2] = *(const s16x8*)(qbase + (size_t)row * 64 + kb2 * 32 + quad * 8);
    }

  float lsum[2] = {0.f, 0.f};
  fx4 oacc[2][4];
#pragma unroll
  for (int qtile = 0; qtile < 2; ++qtile)
#pragma unroll
    for (int dt = 0; dt < 4; ++dt) oacc[qtile][dt] = (fx4){0.f, 0.f, 0.f, 0.f};

  for (int t = t0; t < t1; ++t) {
    int j0 = t * 128;
    bool tail = (j0 + 128 > KSEL);
    __syncthreads();                 // protect prev tile's Kt/Vt reads
#pragma unroll
    for (int p = 0; p < 4; ++p) {    // K-tile: 128 rows x 64 d, coalesced
      int e = p * 256 + tid; int row = e >> 3, kc = e & 7;
      *(s16x8*)(Kt + row * 72 + kc * 8) =
          *(const s16x8*)(kbase + (size_t)(j0 + row) * 64 + kc * 8);
    }
#pragma unroll
    for (int p = 0; p < 4; ++p) {    // Vt-tile: 64 d-rows x 128 tokens, coalesced
      int e = p * 256 + tid; int row = e >> 4, tc = e & 15;
      *(s16x8*)(Vt + row * 136 + tc * 8) =
          *(const s16x8*)(vbase + (size_t)row * KPAD + j0 + tc * 8);
    }
    __syncthreads();

    // two j-halves of 64: S^T -> exp -> wave-private P -> PV
#pragma unroll
    for (int h2 = 0; h2 < 2; ++h2) {
      fx4 sacc[2][4];
#pragma unroll
      for (int qtile = 0; qtile < 2; ++qtile)
#pragma unroll
        for (int jj = 0; jj < 4; ++jj) sacc[qtile][jj] = (fx4){0.f, 0.f, 0.f, 0.f};
#pragma unroll
      for (int jj = 0; jj < 4; ++jj) {
        int jl = h2 * 64 + jj * 16 + l15;
        s16x8 kf0 = *(const s16x8*)(Kt + jl * 72 + quad * 8);
        s16x8 kf1 = *(const s16x8*)(Kt + jl * 72 + 32 + quad * 8);
        sacc[0][jj] = MFMA16(kf0, qf[0][0], sacc[0][jj]);
        sacc[1][jj] = MFMA16(kf0, qf[1][0], sacc[1][jj]);
        sacc[0][jj] = MFMA16(kf1, qf[0][1], sacc[0][jj]);
        sacc[1][jj] = MFMA16(kf1, qf[1][1], sacc[1][jj]);
      }
#pragma unroll
      for (int qtile = 0; qtile < 2; ++qtile)
#pragma unroll
        for (int jj = 0; jj < 4; ++jj) {
          int jbase = j0 + h2 * 64 + jj * 16 + quad * 4;
          fx4 sv = sacc[qtile][jj];
          float p0 = __expf(sv[0] - M);
          float p1 = __expf(sv[1] - M);
          float p2 = __expf(sv[2] - M);
          float p3 = __expf(sv[3] - M);
          if (tail) {
            if (jbase + 0 >= KSEL) p0 = 0.f;
            if (jbase + 1 >= KSEL) p1 = 0.f;
            if (jbase + 2 >= KSEL) p2 = 0.f;
            if (jbase + 3 >= KSEL) p3 = 0.f;
          }
          lsum[qtile] += (p0 + p1) + (p2 + p3);
          unsigned int lo = (fbits(p1) & 0xffff0000u) | (fbits(p0) >> 16);
          unsigned int hi = (fbits(p3) & 0xffff0000u) | (fbits(p2) >> 16);
          *(uint2*)(Pw + (qtile * 16 + l15) * 72 + jj * 16 + quad * 4) =
              make_uint2(lo, hi);
        }
      // PV half: A=P (wave-private LDS), B=V (LDS)
#pragma unroll
      for (int js = 0; js < 2; ++js) {
        s16x8 pf0 = *(const s16x8*)(Pw + l15 * 72 + js * 32 + quad * 8);
        s16x8 pf1 = *(const s16x8*)(Pw + (16 + l15) * 72 + js * 32 + quad * 8);
#pragma unroll
        for (int dt = 0; dt < 4; ++dt) {
          s16x8 vf = *(const s16x8*)(Vt + (dt * 16 + l15) * 136 + h2 * 64 + js * 32 + quad * 8);
          oacc[0][dt] = MFMA16(pf0, vf, oacc[0][dt]);
          oacc[1][dt] = MFMA16(pf1, vf, oacc[1][dt]);
        }
      }
    }
  }

  // combine quad-partitioned j-sums (lanes l15, +16, +32, +48 hold disjoint j sets)
#pragma unroll
  for (int qtile = 0; qtile < 2; ++qtile) {
    float s = lsum[qtile];
    s += __shfl_xor(s, 16);
    s += __shfl_xor(s, 32);
    lsum[qtile] = s;
  }

  size_t pbase = (((size_t)part * 2 + b) * NHQ + h) * KPAD;
#pragma unroll
  for (int qtile = 0; qtile < 2; ++qtile) {
    int gqb = q0 + w * 32 + qtile * 16;
    if (quad == 0) pl[pbase + gqb + l15] = lsum[qtile];
  }

  // transpose O through the (now free) wave-private P buffer -> coalesced stores
#pragma unroll
  for (int qtile = 0; qtile < 2; ++qtile)
#pragma unroll
    for (int dt = 0; dt < 4; ++dt)
#pragma unroll
      for (int r = 0; r < 4; ++r)
        Pw[(qtile * 16 + quad * 4 + r) * 72 + dt * 16 + l15] = f2b(oacc[qtile][dt][r]);
#pragma unroll
  for (int pass = 0; pass < 4; ++pass) {
    int row = pass * 8 + (lane >> 3), chunk = lane & 7;
    s16x8 vv = *(const s16x8*)(Pw + row * 72 + chunk * 8);
    *(s16x8*)(pO + (pbase + q0 + w * 32 + row) * 64 + chunk * 8) = vv;
  }
}

// ---------------- combine the two j-halves: o = (Oa+Ob)/(la+lb) -> ob (bf16) ----------------
__global__ __launch_bounds__(256) void k_comb(const unsigned short* __restrict__ pO,
                                              const float* __restrict__ pl,
                                              unsigned short* __restrict__ ob) {
  size_t g = (size_t)blockIdx.x * 256 + threadIdx.x;   // 2*16*1664*64 = 3407872
  int d = (int)(g & 63);
  size_t row = g >> 6;              // (b*16+h)*1664 + gq
  int gq = (int)(row % KPAD);
  int bhh = (int)(row / KPAD);
  int b = bhh >> 4, h = bhh & 15;
  float oa = b2f(pO[g]);
  float obv = b2f(pO[g + 3407872]);
  float la = pl[row], lb = pl[row + 53248];
  float o = (oa + obv) / (la + lb);
  ob[((size_t)(b * KPAD + gq)) * CQ + h * 64 + d] = f2b(o);
}

extern "C" void kernel_launch(void* const* d_in, const int* in_sizes, int n_in,
                              void* d_out, int out_size, void* d_ws, size_t ws_size,
                              hipStream_t stream) {
  const float* x      = (const float*)d_in[0];
  const float* cached = (const float*)d_in[1];
  const float* wqkv   = (const float*)d_in[2];
  const float* qbias  = (const float*)d_in[3];
  const float* vbias  = (const float*)d_in[4];
  const float* wproj  = (const float*)d_in[5];
  const float* bproj  = (const float*)d_in[6];
  const float* sml    = (const float*)d_in[7];
  const float* rope   = (const float*)d_in[8];
  float* out = (float*)d_out;
  char* ws = (char*)d_ws;

  double* meanpart        = (double*)(ws);                    // 524288
  double* mean            = (double*)(ws + 524288);           // 16384
  double* mse             = (double*)(ws + 540672);           // 65536
  int* idx_sel            = (int*)(ws + 606208);              // 13312 -> 619520
  // overlap zone [619520, 44135424): x_bf + wqkv_bf + qkv (dead after k_normrope)
  unsigned short* x_bf    = (unsigned short*)(ws + 619520);   // 16777216
  unsigned short* wqkv_bf = (unsigned short*)(ws + 17396736); // 6291456
  unsigned short* qkv     = (unsigned short*)(ws + 23688192); // 20447232 -> 44135424
  // attn partials reuse the dead x_bf region
  unsigned short* pO      = (unsigned short*)(ws + 619520);   // 13631488
  float* pl               = (float*)(ws + 14251008);          // 425984 -> 14676992
  unsigned short* wproj_bf= (unsigned short*)(ws + 44135424); // 2097152
  unsigned short* qo      = (unsigned short*)(ws + 46232576); // 6815744
  unsigned short* ko      = (unsigned short*)(ws + 53048320); // 6815744
  unsigned short* vt      = (unsigned short*)(ws + 59864064); // 6815744
  unsigned short* ob      = (unsigned short*)(ws + 66679808); // 6815744 -> 73495552

  hipLaunchKernelGGL(k_cvt3, dim3(12288), dim3(256), 0, stream, x, wqkv, wproj,
                     x_bf, wqkv_bf, wproj_bf);
  hipLaunchKernelGGL(k_mean_part, dim3(256), dim3(256), 0, stream, x, meanpart);
  hipLaunchKernelGGL(k_mean_reduce, dim3(8), dim3(256), 0, stream, meanpart, mean);
  hipLaunchKernelGGL(k_mse_base, dim3(8192), dim3(256), 0, stream, x, cached, mean, mse, out);
  hipLaunchKernelGGL(k_topk, dim3(BQ), dim3(1024), 0, stream, mse, idx_sel);
  hipLaunchKernelGGL((k_gemm<0>), dim3(26 * 24), dim3(256), 0, stream,
                     x_bf, wqkv_bf, idx_sel, qkv, (float*)nullptr,
                     (const float*)nullptr, (const float*)nullptr);
  hipLaunchKernelGGL(k_normrope, dim3(26 * 16 * BQ), dim3(256), 0, stream,
                     qkv, idx_sel, qbias, vbias, sml, rope, qo, ko, vt);
  hipLaunchKernelGGL(k_attn, dim3(13, BQ * NHQ, 2), dim3(256), 0, stream,
                     qo, ko, vt, sml, pO, pl);
  hipLaunchKernelGGL(k_comb, dim3(13312), dim3(256), 0, stream, pO, pl, ob);
  hipLaunchKernelGGL((k_gemm<1>), dim3(26 * 8), dim3(256), 0, stream,
                     ob, wproj_bf, idx_sel, (unsigned short*)nullptr, out, x, bproj);
}

// Round 7
// 331.792 us; speedup vs baseline: 1.2862x; 1.2862x over previous
//
#include <hip/hip_runtime.h>
#include <hip/hip_bf16.h>
#include <math.h>

// Problem constants (setup_inputs)
#define BQ   2
#define LQ   4096
#define CQ   1024
#define NHQ  16
#define DHQ  64
#define KSEL 1638
#define KPAD 1664
#define MTOT (BQ*KSEL)   // 3276
#define MPAD 3328        // 26*128

typedef short s16x8 __attribute__((ext_vector_type(8)));
typedef float fx4   __attribute__((ext_vector_type(4)));

#define MFMA16(a,b,c) __builtin_amdgcn_mfma_f32_16x16x32_bf16(a,b,c,0,0,0)

__device__ __forceinline__ float b2f(unsigned short u) {
  union { float f; unsigned int i; } cv; cv.i = ((unsigned int)u) << 16; return cv.f;
}
__device__ __forceinline__ unsigned short f2b(float f) {
  union { float f; unsigned int i; } cv; cv.f = f;
  unsigned int x = cv.i;
  return (unsigned short)((x + 0x7fffu + ((x >> 16) & 1u)) >> 16);
}
__device__ __forceinline__ unsigned int fbits(float f) {
  union { float f; unsigned int i; } cv; cv.f = f; return cv.i;
}
__device__ __forceinline__ void async16(const void* g, void* l) {
  __builtin_amdgcn_global_load_lds((const __attribute__((address_space(1))) void*)g,
                                   (__attribute__((address_space(3))) void*)l, 16, 0, 0);
}

// ---------------- fp32 -> bf16 conversion, fused over x / W_qkv / W_proj ----------------
__global__ __launch_bounds__(256) void k_cvt3(const float* __restrict__ x,
                                              const float* __restrict__ wqkv,
                                              const float* __restrict__ wproj,
                                              unsigned short* __restrict__ xb,
                                              unsigned short* __restrict__ wqb,
                                              unsigned short* __restrict__ wpb) {
  int i = blockIdx.x * 256 + threadIdx.x;   // float4 index, total 3145728
  const float* s; unsigned short* d; int off;
  if (i < 2097152)      { s = x;     d = xb;  off = i; }
  else if (i < 2883584) { s = wqkv;  d = wqb; off = i - 2097152; }
  else                  { s = wproj; d = wpb; off = i - 2883584; }
  float4 v = ((const float4*)s)[off];
  ushort4 o;
  o.x = f2b(v.x); o.y = f2b(v.y); o.z = f2b(v.z); o.w = f2b(v.w);
  ((ushort4*)d)[off] = o;
}

// ---------------- mean (fp64, 2-stage) ----------------
__global__ __launch_bounds__(256) void k_mean_part(const float* __restrict__ x,
                                                   double* __restrict__ part) {
  int bid = blockIdx.x;                    // 256 blocks: [b(2)][ch(32)][cb(4)]
  int cb = bid & 3, ch = (bid >> 2) & 31, b = bid >> 7;
  int c = cb * 256 + threadIdx.x;
  const float* p = x + ((size_t)b * LQ + (size_t)ch * 128) * CQ + c;
  double s = 0.0;
  for (int r = 0; r < 128; ++r) s += (double)p[(size_t)r * CQ];
  part[((size_t)b * 32 + ch) * CQ + c] = s;
}

__global__ __launch_bounds__(256) void k_mean_reduce(const double* __restrict__ part,
                                                     double* __restrict__ mean) {
  int g = blockIdx.x * 256 + threadIdx.x;  // 2048 = B*C
  int b = g >> 10, c = g & 1023;
  double s = 0.0;
  for (int ch = 0; ch < 32; ++ch) s += part[((size_t)b * 32 + ch) * CQ + c];
  mean[g] = s * (1.0 / 4096.0);
}

// ---------------- mse (fp64) + base output (x + upsample(cached)) ----------------
__global__ __launch_bounds__(256) void k_mse_base(const float* __restrict__ x,
                                                  const float* __restrict__ cached,
                                                  const double* __restrict__ mean,
                                                  double* __restrict__ mse,
                                                  float* __restrict__ out) {
  int bl = blockIdx.x; int b = bl >> 12, l = bl & 4095;
  int hh = l >> 6, ww = l & 63;
  size_t xoff = ((size_t)b * LQ + l) * CQ;
  size_t uoff = (((size_t)b * 32 + (hh >> 1)) * 32 + (ww >> 1)) * CQ;
  const double* mrow = mean + (size_t)b * CQ;
  int c0 = threadIdx.x * 4;
  float4 xv = *(const float4*)(x + xoff + c0);
  float4 uv = *(const float4*)(cached + uoff + c0);
  float4 ov;
  ov.x = xv.x + uv.x; ov.y = xv.y + uv.y; ov.z = xv.z + uv.z; ov.w = xv.w + uv.w;
  *(float4*)(out + xoff + c0) = ov;
  double d0 = (double)xv.x - mrow[c0];
  double d1 = (double)xv.y - mrow[c0 + 1];
  double d2 = (double)xv.z - mrow[c0 + 2];
  double d3 = (double)xv.w - mrow[c0 + 3];
  double ss = d0 * d0 + d1 * d1 + d2 * d2 + d3 * d3;
  for (int o = 1; o < 64; o <<= 1) ss += __shfl_xor(ss, o);
  __shared__ double ws4[4];
  if ((threadIdx.x & 63) == 0) ws4[threadIdx.x >> 6] = ss;
  __syncthreads();
  if (threadIdx.x == 0) mse[(size_t)b * LQ + l] = ws4[0] + ws4[1] + ws4[2] + ws4[3];
}

// ---------------- top-k: MSD radix select, parallel suffix-scan bin selection ----------------
// R6 post-mortem: the cost was never atomics — it was the t==0 serial 256-bin scan
// (8 passes x 256 x ~120cyc LDS latency ~= 102us). Replace with a 256-thread suffix
// scan (shfl_up within wave + 4 wave totals): ~1us total for all passes.
__global__ __launch_bounds__(1024) void k_topk(const double* __restrict__ mse,
                                               int* __restrict__ idx_sel) {
  __shared__ unsigned long long u[4096];       // 32 KB
  __shared__ unsigned int whist[16 * 257];     // 16.4 KB, stride 257 => cross-wave bank skew
  __shared__ unsigned int wtot[4];
  __shared__ unsigned long long sh_prefix;
  __shared__ int sh_rem, sh_rem2, sh_bsel, sh_cnt, sh_eqcnt;
  __shared__ int eqbuf[256];
  int b = blockIdx.x, t = threadIdx.x;
  int wv = t >> 6, laneid = t & 63;
  for (int p = 0; p < 4; ++p) {
    int i = p * 1024 + t;
    u[i] = (unsigned long long)__double_as_longlong(mse[(size_t)b * LQ + i]);
  }
  if (t == 0) { sh_prefix = 0ULL; sh_rem = KSEL; sh_cnt = 0; sh_eqcnt = 0; }
  __syncthreads();
  for (int shift = 56; shift >= 0; shift -= 8) {
    for (int z = t; z < 16 * 257; z += 1024) whist[z] = 0u;
    __syncthreads();
    unsigned long long pref = sh_prefix;
#pragma unroll
    for (int p = 0; p < 4; ++p) {
      int i = p * 1024 + t;
      unsigned long long v = u[i];
      bool cand = (shift == 56) || ((v >> ((shift + 8) & 63)) == pref);
      if (cand) atomicAdd(&whist[wv * 257 + ((unsigned int)(v >> shift) & 255u)], 1u);
    }
    __syncthreads();
    unsigned int myc = 0, mysc = 0;
    if (t < 256) {            // combine the 16 wave hists for my bin (bin = 255 - t)
      unsigned int s = 0;
      int bin = 255 - t;
#pragma unroll
      for (int wvi = 0; wvi < 16; ++wvi) s += whist[wvi * 257 + bin];
      myc = s;
      // inclusive scan in thread order (= descending bin order) across the wave
      mysc = myc;
#pragma unroll
      for (int o = 1; o < 64; o <<= 1) {
        unsigned int v2 = __shfl_up(mysc, o);
        if (laneid >= o) mysc += v2;
      }
      if (laneid == 63) wtot[wv] = mysc;
    }
    __syncthreads();
    if (t < 256) {
      unsigned int basep = 0;
      for (int wvi = 0; wvi < wv; ++wvi) basep += wtot[wvi];
      unsigned int incl = basep + mysc;       // count of keys in bins >= my bin
      unsigned int excl = incl - myc;         // count of keys in bins >  my bin
      unsigned int rem = (unsigned int)sh_rem;
      if (excl < rem && rem <= incl) {        // exactly one thread crosses
        sh_bsel = 255 - t;
        sh_rem2 = (int)(rem - excl);
      }
    }
    __syncthreads();
    if (t == 0) {
      sh_prefix = (sh_prefix << 8) | (unsigned long long)sh_bsel;
      sh_rem = sh_rem2;
    }
    __syncthreads();
  }
  unsigned long long T = sh_prefix;
  int rem_eq = sh_rem;
#pragma unroll
  for (int p = 0; p < 4; ++p) {
    int i = p * 1024 + t;
    unsigned long long v = u[i];
    bool win = (v > T);
    unsigned long long mask = __ballot(win);
    int total = __popcll(mask);
    int base = 0;
    if (laneid == 0 && total > 0) base = atomicAdd(&sh_cnt, total);
    base = __shfl(base, 0);
    if (win) {
      int lpos = __popcll(mask & ((1ULL << laneid) - 1ULL));
      idx_sel[b * KPAD + base + lpos] = i;
    }
    if (v == T) {
      int e = atomicAdd(&sh_eqcnt, 1);
      if (e < 256) eqbuf[e] = i;
    }
  }
  __syncthreads();
  if (t == 0) {
    int n = sh_eqcnt; if (n > 256) n = 256;
    for (int a = 1; a < n; ++a) {           // ascending index sort (ties: smallest index wins)
      int key = eqbuf[a]; int c = a - 1;
      while (c >= 0 && eqbuf[c] > key) { eqbuf[c + 1] = eqbuf[c]; --c; }
      eqbuf[c + 1] = key;
    }
    int base = sh_cnt;
    for (int a = 0; a < rem_eq && a < n; ++a) idx_sel[b * KPAD + base + a] = eqbuf[a];
    for (int a = KSEL; a < KPAD; ++a) idx_sel[b * KPAD + a] = 0;
  }
}

// ---------------- GEMM (m97-style 128x128, BK=32, global_load_lds w16) ----------------
template<int MODE>
__global__ __launch_bounds__(256) void k_gemm(const unsigned short* __restrict__ Asrc,
                                              const unsigned short* __restrict__ Bmat,
                                              const int* __restrict__ idx_sel,
                                              unsigned short* __restrict__ Cbf,
                                              float* __restrict__ Cf,
                                              const float* __restrict__ xin,
                                              const float* __restrict__ bproj) {
  int bm = blockIdx.x % 26, bn = blockIdx.x / 26;
  int tid = threadIdx.x;
  int w = tid >> 6, lane = tid & 63, quad = lane >> 4, l15 = lane & 15;
  int wm = w & 1, wn = w >> 1;
  __shared__ __align__(16) unsigned char sm[16384];   // A [128][32]bf16, B [128][32]bf16

  const unsigned short* gA[2];
  const unsigned short* gB[2];
#pragma unroll
  for (int p = 0; p < 2; ++p) {
    int e = p * 256 + tid; int row = e >> 2, kc = e & 3;
    int m = bm * 128 + row; if (m >= MTOT) m = MTOT - 1;
    int bb = m / KSEL; int ii = m - bb * KSEL;
    const unsigned short* rp;
    if (MODE == 0) {
      int lsel = idx_sel[bb * KPAD + ii];
      rp = Asrc + ((size_t)bb * LQ + lsel) * CQ;
    } else {
      rp = Asrc + ((size_t)bb * KPAD + ii) * CQ;
    }
    gA[p] = rp + kc * 8;
    gB[p] = Bmat + (size_t)(bn * 128 + row) * CQ + kc * 8;
  }

  fx4 acc[4][4];
#pragma unroll
  for (int a = 0; a < 4; ++a)
#pragma unroll
    for (int c = 0; c < 4; ++c) acc[a][c] = (fx4){0.f, 0.f, 0.f, 0.f};

  for (int it = 0; it < 32; ++it) {
    int ke = it * 32;
    __syncthreads();
#pragma unroll
    for (int p = 0; p < 2; ++p) {
      async16(gA[p] + ke, sm + p * 4096 + w * 1024);
      async16(gB[p] + ke, sm + 8192 + p * 4096 + w * 1024);
    }
    __syncthreads();
    s16x8 af[4], bf[4];
#pragma unroll
    for (int mt = 0; mt < 4; ++mt)
      af[mt] = *(const s16x8*)(sm + ((wm * 64 + mt * 16 + l15) * 64 + quad * 16));
#pragma unroll
    for (int nt = 0; nt < 4; ++nt)
      bf[nt] = *(const s16x8*)(sm + 8192 + ((wn * 64 + nt * 16 + l15) * 64 + quad * 16));
#pragma unroll
    for (int mt = 0; mt < 4; ++mt)
#pragma unroll
      for (int nt = 0; nt < 4; ++nt)
        acc[mt][nt] = MFMA16(af[mt], bf[nt], acc[mt][nt]);
  }

#pragma unroll
  for (int mt = 0; mt < 4; ++mt)
#pragma unroll
    for (int nt = 0; nt < 4; ++nt) {
      int n = bn * 128 + wn * 64 + nt * 16 + l15;
      int mbase = bm * 128 + wm * 64 + mt * 16 + quad * 4;
      fx4 vv = acc[mt][nt];
      if (MODE == 0) {
#pragma unroll
        for (int r = 0; r < 4; ++r) {
          int m = mbase + r;
          if (m < MTOT) Cbf[(size_t)m * 3072 + n] = f2b(vv[r]);
        }
      } else {
        float bp = bproj[n];
#pragma unroll
        for (int r = 0; r < 4; ++r) {
          int m = mbase + r;
          if (m < MTOT) {
            int bb = m / KSEL; int ii = m - bb * KSEL;
            int lsel = idx_sel[bb * KPAD + ii];
            size_t off = ((size_t)bb * LQ + lsel) * CQ + n;
            Cf[off] = xin[off] + vv[r] + bp;
          }
        }
      }
    }
}

// ---------------- l2norm + scale + rope -> q,k ; v -> Vt (transposed) ----------------
__global__ __launch_bounds__(256) void k_normrope(const unsigned short* __restrict__ qkv,
                                                  const int* __restrict__ idx_sel,
                                                  const float* __restrict__ qbias,
                                                  const float* __restrict__ vbias,
                                                  const float* __restrict__ sml,
                                                  const float* __restrict__ rope,
                                                  unsigned short* __restrict__ qo,
                                                  unsigned short* __restrict__ ko,
                                                  unsigned short* __restrict__ vt) {
  int bid = blockIdx.x;                       // 26*16*2
  int tile = bid % 26; int h = (bid / 26) & 15; int b = bid / (26 * 16);
  int tid = threadIdx.x; int w = tid >> 6; int d = tid & 63;
  __shared__ unsigned short vtile[64 * 68];
  float scale = expf(fminf(sml[h], 4.6051702f));
  float qb = qbias[h * 64 + d];
  float vb = vbias[h * 64 + d];
  for (int pass = 0; pass < 16; ++pass) {
    int il = pass * 4 + w;
    int i = tile * 64 + il;
    float vraw = 0.f;
    if (i < KSEL) {
      int lsel = idx_sel[b * KPAD + i];
      size_t base = ((size_t)(b * KSEL + i)) * 3072 + h * 64 + d;
      int tt = d >> 1;
      float r0 = rope[(size_t)lsel * 32 + tt];
      float r1 = rope[(size_t)LQ * 32 + (size_t)lsel * 32 + tt];
      // q
      float qv = b2f(qkv[base]) + qb;
      float ss = qv * qv;
      for (int o = 1; o < 64; o <<= 1) ss += __shfl_xor(ss, o);
      float qn = qv / fmaxf(sqrtf(ss), 1e-12f) * scale;
      float qp = __shfl_xor(qn, 1);
      float qr = (d & 1) ? (r1 * qp + r0 * qn) : (r0 * qn - r1 * qp);
      qo[((size_t)(b * NHQ + h) * KPAD + i) * 64 + d] = f2b(qr);
      // k
      float kv = b2f(qkv[base + 1024]);
      float ks = kv * kv;
      for (int o = 1; o < 64; o <<= 1) ks += __shfl_xor(ks, o);
      float kn = kv / fmaxf(sqrtf(ks), 1e-12f);
      float kp = __shfl_xor(kn, 1);
      float kr = (d & 1) ? (r1 * kp + r0 * kn) : (r0 * kn - r1 * kp);
      ko[((size_t)(b * NHQ + h) * KPAD + i) * 64 + d] = f2b(kr);
      vraw = b2f(qkv[base + 2048]) + vb;
    }
    vtile[d * 68 + il] = f2b(vraw);
  }
  __syncthreads();
  int row = tid >> 2, c0 = (tid & 3) * 16;
  s16x8 o0, o1;
#pragma unroll
  for (int jj = 0; jj < 8; ++jj) {
    o0[jj] = (short)vtile[row * 68 + c0 + jj];
    o1[jj] = (short)vtile[row * 68 + c0 + 8 + jj];
  }
  size_t doff = ((size_t)((b * NHQ + h) * 64 + row)) * KPAD + (size_t)tile * 64 + c0;
  *(s16x8*)(vt + doff) = o0;
  *(s16x8*)(vt + doff + 8) = o1;
}

// ---------------- flash attention: S^T trick + LDS staging + coalesced epilogue ----------------
__global__ __launch_bounds__(256, 4) void k_attn(const unsigned short* __restrict__ qb,
                                                 const unsigned short* __restrict__ kb,
                                                 const unsigned short* __restrict__ vtb,
                                                 const float* __restrict__ sml,
                                                 unsigned short* __restrict__ pO,
                                                 float* __restrict__ pl) {
  int qt = blockIdx.x; int bh = blockIdx.y; int part = blockIdx.z;
  int b = bh >> 4, h = bh & 15;
  int t0 = part ? 7 : 0, t1 = part ? 13 : 7;
  int q0 = qt * 128;
  int tid = threadIdx.x, w = tid >> 6, lane = tid & 63, quad = lane >> 4, l15 = lane & 15;
  float M = __expf(fminf(sml[h], 4.6051702f));   // |S| <= scale, fixed softmax shift
  __shared__ __align__(16) unsigned short Kt[128 * 72];    // 18432 B
  __shared__ __align__(16) unsigned short Vt[64 * 136];    // 17408 B
  __shared__ __align__(16) unsigned short Pq[4][32 * 72];  // 18432 B  (total 54272 -> 3 blk/CU)
  unsigned short* Pw = Pq[w];
  const unsigned short* qbase = qb + (size_t)(b * NHQ + h) * KPAD * 64;
  const unsigned short* kbase = kb + (size_t)(b * NHQ + h) * KPAD * 64;
  const unsigned short* vbase = vtb + (size_t)(b * NHQ + h) * 64 * KPAD;

  // Q as B-operand: n=l15 -> q row; k = kb2*32 + quad*8
  s16x8 qf[2][2];
#pragma unroll
  for (int qtile = 0; qtile < 2; ++qtile)
#pragma unroll
    for (int kb2 = 0; kb2 < 2; ++kb2) {
      int row = q0 + w * 32 + qtile * 16 + l15;
      qf[qtile][kb2] = *(const s16x8*)(qbase + (size_t)row * 64 + kb2 * 32 + quad * 8);
    }

  float lsum[2] = {0.f, 0.f};
  fx4 oacc[2][4];
#pragma unroll
  for (int qtile = 0; qtile < 2; ++qtile)
#pragma unroll
    for (int dt = 0; dt < 4; ++dt) oacc[qtile][dt] = (fx4){0.f, 0.f, 0.f, 0.f};

  for (int t = t0; t < t1; ++t) {
    int j0 = t * 128;
    bool tail = (j0 + 128 > KSEL);
    __syncthreads();                 // protect prev tile's Kt/Vt reads
#pragma unroll
    for (int p = 0; p < 4; ++p) {    // K-tile: 128 rows x 64 d, coalesced
      int e = p * 256 + tid; int row = e >> 3, kc = e & 7;
      *(s16x8*)(Kt + row * 72 + kc * 8) =
          *(const s16x8*)(kbase + (size_t)(j0 + row) * 64 + kc * 8);
    }
#pragma unroll
    for (int p = 0; p < 4; ++p) {    // Vt-tile: 64 d-rows x 128 tokens, coalesced
      int e = p * 256 + tid; int row = e >> 4, tc = e & 15;
      *(s16x8*)(Vt + row * 136 + tc * 8) =
          *(const s16x8*)(vbase + (size_t)row * KPAD + j0 + tc * 8);
    }
    __syncthreads();

    // two j-halves of 64: S^T -> exp -> wave-private P -> PV
#pragma unroll
    for (int h2 = 0; h2 < 2; ++h2) {
      fx4 sacc[2][4];
#pragma unroll
      for (int qtile = 0; qtile < 2; ++qtile)
#pragma unroll
        for (int jj = 0; jj < 4; ++jj) sacc[qtile][jj] = (fx4){0.f, 0.f, 0.f, 0.f};
#pragma unroll
      for (int jj = 0; jj < 4; ++jj) {
        int jl = h2 * 64 + jj * 16 + l15;
        s16x8 kf0 = *(const s16x8*)(Kt + jl * 72 + quad * 8);
        s16x8 kf1 = *(const s16x8*)(Kt + jl * 72 + 32 + quad * 8);
        sacc[0][jj] = MFMA16(kf0, qf[0][0], sacc[0][jj]);
        sacc[1][jj] = MFMA16(kf0, qf[1][0], sacc[1][jj]);
        sacc[0][jj] = MFMA16(kf1, qf[0][1], sacc[0][jj]);
        sacc[1][jj] = MFMA16(kf1, qf[1][1], sacc[1][jj]);
      }
#pragma unroll
      for (int qtile = 0; qtile < 2; ++qtile)
#pragma unroll
        for (int jj = 0; jj < 4; ++jj) {
          int jbase = j0 + h2 * 64 + jj * 16 + quad * 4;
          fx4 sv = sacc[qtile][jj];
          float p0 = __expf(sv[0] - M);
          float p1 = __expf(sv[1] - M);
          float p2 = __expf(sv[2] - M);
          float p3 = __expf(sv[3] - M);
          if (tail) {
            if (jbase + 0 >= KSEL) p0 = 0.f;
            if (jbase + 1 >= KSEL) p1 = 0.f;
            if (jbase + 2 >= KSEL) p2 = 0.f;
            if (jbase + 3 >= KSEL) p3 = 0.f;
          }
          lsum[qtile] += (p0 + p1) + (p2 + p3);
          unsigned int lo = (fbits(p1) & 0xffff0000u) | (fbits(p0) >> 16);
          unsigned int hi = (fbits(p3) & 0xffff0000u) | (fbits(p2) >> 16);
          *(uint2*)(Pw + (qtile * 16 + l15) * 72 + jj * 16 + quad * 4) =
              make_uint2(lo, hi);
        }
      // PV half: A=P (wave-private LDS), B=V (LDS)
#pragma unroll
      for (int js = 0; js < 2; ++js) {
        s16x8 pf0 = *(const s16x8*)(Pw + l15 * 72 + js * 32 + quad * 8);
        s16x8 pf1 = *(const s16x8*)(Pw + (16 + l15) * 72 + js * 32 + quad * 8);
#pragma unroll
        for (int dt = 0; dt < 4; ++dt) {
          s16x8 vf = *(const s16x8*)(Vt + (dt * 16 + l15) * 136 + h2 * 64 + js * 32 + quad * 8);
          oacc[0][dt] = MFMA16(pf0, vf, oacc[0][dt]);
          oacc[1][dt] = MFMA16(pf1, vf, oacc[1][dt]);
        }
      }
    }
  }

  // combine quad-partitioned j-sums (lanes l15, +16, +32, +48 hold disjoint j sets)
#pragma unroll
  for (int qtile = 0; qtile < 2; ++qtile) {
    float s = lsum[qtile];
    s += __shfl_xor(s, 16);
    s += __shfl_xor(s, 32);
    lsum[qtile] = s;
  }

  size_t pbase = (((size_t)part * 2 + b) * NHQ + h) * KPAD;
#pragma unroll
  for (int qtile = 0; qtile < 2; ++qtile) {
    int gqb = q0 + w * 32 + qtile * 16;
    if (quad == 0) pl[pbase + gqb + l15] = lsum[qtile];
  }

  // transpose O through the (now free) wave-private P buffer -> coalesced stores
#pragma unroll
  for (int qtile = 0; qtile < 2; ++qtile)
#pragma unroll
    for (int dt = 0; dt < 4; ++dt)
#pragma unroll
      for (int r = 0; r < 4; ++r)
        Pw[(qtile * 16 + quad * 4 + r) * 72 + dt * 16 + l15] = f2b(oacc[qtile][dt][r]);
#pragma unroll
  for (int pass = 0; pass < 4; ++pass) {
    int row = pass * 8 + (lane >> 3), chunk = lane & 7;
    s16x8 vv = *(const s16x8*)(Pw + row * 72 + chunk * 8);
    *(s16x8*)(pO + (pbase + q0 + w * 32 + row) * 64 + chunk * 8) = vv;
  }
}

// ---------------- combine the two j-halves: o = (Oa+Ob)/(la+lb) -> ob (bf16) ----------------
__global__ __launch_bounds__(256) void k_comb(const unsigned short* __restrict__ pO,
                                              const float* __restrict__ pl,
                                              unsigned short* __restrict__ ob) {
  size_t g = (size_t)blockIdx.x * 256 + threadIdx.x;   // 2*16*1664*64 = 3407872
  int d = (int)(g & 63);
  size_t row = g >> 6;              // (b*16+h)*1664 + gq
  int gq = (int)(row % KPAD);
  int bhh = (int)(row / KPAD);
  int b = bhh >> 4, h = bhh & 15;
  float oa = b2f(pO[g]);
  float obv = b2f(pO[g + 3407872]);
  float la = pl[row], lb = pl[row + 53248];
  float o = (oa + obv) / (la + lb);
  ob[((size_t)(b * KPAD + gq)) * CQ + h * 64 + d] = f2b(o);
}

extern "C" void kernel_launch(void* const* d_in, const int* in_sizes, int n_in,
                              void* d_out, int out_size, void* d_ws, size_t ws_size,
                              hipStream_t stream) {
  const float* x      = (const float*)d_in[0];
  const float* cached = (const float*)d_in[1];
  const float* wqkv   = (const float*)d_in[2];
  const float* qbias  = (const float*)d_in[3];
  const float* vbias  = (const float*)d_in[4];
  const float* wproj  = (const float*)d_in[5];
  const float* bproj  = (const float*)d_in[6];
  const float* sml    = (const float*)d_in[7];
  const float* rope   = (const float*)d_in[8];
  float* out = (float*)d_out;
  char* ws = (char*)d_ws;

  double* meanpart        = (double*)(ws);                    // 524288
  double* mean            = (double*)(ws + 524288);           // 16384
  double* mse             = (double*)(ws + 540672);           // 65536
  int* idx_sel            = (int*)(ws + 606208);              // 13312 -> 619520
  // overlap zone [619520, 44135424): x_bf + wqkv_bf + qkv (dead after k_normrope)
  unsigned short* x_bf    = (unsigned short*)(ws + 619520);   // 16777216
  unsigned short* wqkv_bf = (unsigned short*)(ws + 17396736); // 6291456
  unsigned short* qkv     = (unsigned short*)(ws + 23688192); // 20447232 -> 44135424
  // attn partials reuse the dead x_bf region
  unsigned short* pO      = (unsigned short*)(ws + 619520);   // 13631488
  float* pl               = (float*)(ws + 14251008);          // 425984 -> 14676992
  unsigned short* wproj_bf= (unsigned short*)(ws + 44135424); // 2097152
  unsigned short* qo      = (unsigned short*)(ws + 46232576); // 6815744
  unsigned short* ko      = (unsigned short*)(ws + 53048320); // 6815744
  unsigned short* vt      = (unsigned short*)(ws + 59864064); // 6815744
  unsigned short* ob      = (unsigned short*)(ws + 66679808); // 6815744 -> 73495552

  hipLaunchKernelGGL(k_cvt3, dim3(12288), dim3(256), 0, stream, x, wqkv, wproj,
                     x_bf, wqkv_bf, wproj_bf);
  hipLaunchKernelGGL(k_mean_part, dim3(256), dim3(256), 0, stream, x, meanpart);
  hipLaunchKernelGGL(k_mean_reduce, dim3(8), dim3(256), 0, stream, meanpart, mean);
  hipLaunchKernelGGL(k_mse_base, dim3(8192), dim3(256), 0, stream, x, cached, mean, mse, out);
  hipLaunchKernelGGL(k_topk, dim3(BQ), dim3(1024), 0, stream, mse, idx_sel);
  hipLaunchKernelGGL((k_gemm<0>), dim3(26 * 24), dim3(256), 0, stream,
                     x_bf, wqkv_bf, idx_sel, qkv, (float*)nullptr,
                     (const float*)nullptr, (const float*)nullptr);
  hipLaunchKernelGGL(k_normrope, dim3(26 * 16 * BQ), dim3(256), 0, stream,
                     qkv, idx_sel, qbias, vbias, sml, rope, qo, ko, vt);
  hipLaunchKernelGGL(k_attn, dim3(13, BQ * NHQ, 2), dim3(256), 0, stream,
                     qo, ko, vt, sml, pO, pl);
  hipLaunchKernelGGL(k_comb, dim3(13312), dim3(256), 0, stream, pO, pl, ob);
  hipLaunchKernelGGL((k_gemm<1>), dim3(26 * 8), dim3(256), 0, stream,
                     ob, wproj_bf, idx_sel, (unsigned short*)nullptr, out, x, bproj);
}